// Round 1
// 438.480 us; speedup vs baseline: 1.8125x; 1.8125x over previous
//
#include <hip/hip_runtime.h>
#include <stdint.h>
#include <math.h>

#define HW    524288      // 512*1024 pixels
#define NETA  7
#define F     68          // NPROG*LEV
#define OC    17          // outputs per thread (F/4)

// LDS layout for W: per-expert stride padded 4624 -> 4628 words so expert bases
// hit banks (20*e)%32 = {0,20,8,28,16,4,24} -> a b128 read with <=7 unique
// per-lane addresses (one per expert) touches 28 distinct banks: conflict-free.
#define WSTRIDE 4628
#define WLDS_W  (6 * WSTRIDE + 4624)        // 32392 words of W
#define LDS_TOT (WLDS_W + NETA * F)         // + 476 words of bias = 131472 B

// ---------------- threefry2x32, key = (0, 42)  [jax.random.key(42)] ----------------
// jax_threefry_partitionable=True (default): counter=(0,i), bits = o0 ^ o1.
// Verified bit-exact vs np reference in a previous round (absmax 0.0).
__device__ __forceinline__ uint32_t threefry_xor_k42(uint32_t x0, uint32_t x1) {
  const uint32_t ks0 = 0u;
  const uint32_t ks1 = 42u;
  const uint32_t ks2 = 0x1BD11BDAu ^ ks0 ^ ks1;
  x0 += ks0; x1 += ks1;
#define RND(r) { x0 += x1; x1 = (x1 << (r)) | (x1 >> (32 - (r))); x1 ^= x0; }
  RND(13) RND(15) RND(26) RND(6)   x0 += ks1; x1 += ks2 + 1u;
  RND(17) RND(29) RND(16) RND(24)  x0 += ks2; x1 += ks0 + 2u;
  RND(13) RND(15) RND(26) RND(6)   x0 += ks0; x1 += ks1 + 3u;
  RND(17) RND(29) RND(16) RND(24)  x0 += ks1; x1 += ks2 + 4u;
  RND(13) RND(15) RND(26) RND(6)   x0 += ks2; x1 += ks0 + 5u;
#undef RND
  return x0 ^ x1;
}

// ---------------- kernel 1: categorical sampling via exponential race ----------------
// argmax_k [gumbel_k + log(T[r,k]+1e-9)]  ==  argmin_k [(-ln u_k) / (T[r,k]+1e-9)]
// f32 screen with hw v_log_f32; f64 fallback when top-2 relative gap < 3e-5.
__global__ void __launch_bounds__(256) eta_kernel(const float* __restrict__ T,
                                                  const int* __restrict__ eta,
                                                  int* __restrict__ eta_new) {
  __shared__ float  rinv32[NETA * NETA];
  __shared__ double rinv64[NETA * NETA];
  const int tid = threadIdx.x;
  if (tid < NETA * NETA) {
    double d = 1.0 / ((double)T[tid] + 1e-9);
    rinv64[tid] = d;
    rinv32[tid] = (float)d;
  }
  __syncthreads();

  const int p = blockIdx.x * 256 + tid;
  const int r = eta[p];

  float w[NETA];
#pragma unroll
  for (int k = 0; k < NETA; k++) {
    const uint32_t bits = threefry_xor_k42(0u, (uint32_t)(7 * p + k));
    const float f = __uint_as_float((bits >> 9) | 0x3f800000u) - 1.0f;
    const float u = (f == 0.0f) ? 1.1754943508222875e-38f : f;
    w[k] = (-__log2f(u)) * rinv32[r * NETA + k];
  }
  float w1 = w[0], w2 = 3.4e38f;
  int e = 0;
#pragma unroll
  for (int k = 1; k < NETA; k++) {
    if (w[k] < w1)      { w2 = w1; w1 = w[k]; e = k; }
    else if (w[k] < w2) { w2 = w[k]; }
  }
  if (!((w2 - w1) > 3e-5f * w2)) {           // ambiguous -> exact f64 race (rare)
    double b1 = 1e300;
    e = 0;
    for (int k = 0; k < NETA; k++) {
      const uint32_t bits = threefry_xor_k42(0u, (uint32_t)(7 * p + k));
      const float f = __uint_as_float((bits >> 9) | 0x3f800000u) - 1.0f;
      const double u = (f == 0.0f) ? (double)1.1754943508222875e-38f : (double)f;
      const double wv = -log(u) * rinv64[r * NETA + k];
      if (wv < b1) { b1 = wv; e = k; }
    }
  }
  eta_new[p] = e;
}

// ---------------- kernel 2: selected-expert matvec, W broadcast from LDS ----------------
// Block = 64 pixels x 4 o-chunks. ALL of W (+bias) staged in LDS (131.5 KB ->
// 1 block/CU), amortized over 8 pixel-tiles via grid-stride. Inner loop is pure
// LDS-broadcast (<=7 unique addrs/wave, padded stride -> 0 bank conflicts) + FMA.
// x read direct from global: coalesced dword loads, 17 KB/tile working set
// stays L1-resident across the 4 c-chunk waves.
__global__ void __launch_bounds__(256, 1) expert_kernel(const float* __restrict__ x,
                                                        const float* __restrict__ W,
                                                        const float* __restrict__ b,
                                                        const int* __restrict__ eta_new,
                                                        float* __restrict__ out) {
  __shared__ __align__(16) float wlds[LDS_TOT];
  const int tid = threadIdx.x;

  // stage W: contiguous per expert, 1156 float4 each
#pragma unroll
  for (int e = 0; e < NETA; e++) {
    const float* __restrict__ src = W + (size_t)e * (F * F);
    float* dst = wlds + e * WSTRIDE;
    for (int i = tid; i < (F * F) / 4; i += 256) {
      *reinterpret_cast<float4*>(dst + 4 * i) =
          *reinterpret_cast<const float4*>(src + 4 * i);
    }
  }
  for (int i = tid; i < NETA * F; i += 256) wlds[WLDS_W + i] = b[i];
  __syncthreads();

  const int pl = tid & 63;                   // pixel lane within tile
  const int c  = tid >> 6;                   // o-chunk 0..3

  for (int tile = blockIdx.x; tile < HW / 64; tile += gridDim.x) {
    const int p = tile * 64 + pl;
    const int e = eta_new[p];

    // full x column for this pixel: 68 coalesced dword loads (static indices)
    float xv[F];
#pragma unroll
    for (int f = 0; f < F; f++) xv[f] = x[(size_t)f * HW + p];

    const float* wp = wlds + e * WSTRIDE + (c * OC) * F;

    float acc[OC];
#pragma unroll
    for (int o = 0; o < OC; o++) acc[o] = 0.0f;

    // fully unrolled: every xv/acc index static (registers), W via ds_read_b128
#pragma unroll
    for (int f4 = 0; f4 < F / 4; f4++) {
      const float x0 = xv[4 * f4 + 0];
      const float x1 = xv[4 * f4 + 1];
      const float x2 = xv[4 * f4 + 2];
      const float x3 = xv[4 * f4 + 3];
#pragma unroll
      for (int o = 0; o < OC; o++) {
        const float4 w = *reinterpret_cast<const float4*>(wp + o * F + 4 * f4);
        float a = acc[o];
        a = fmaf(w.x, x0, a);
        a = fmaf(w.y, x1, a);
        a = fmaf(w.z, x2, a);
        a = fmaf(w.w, x3, a);
        acc[o] = a;
      }
    }

#pragma unroll
    for (int o = 0; o < OC; o++)
      out[(size_t)(c * OC + o) * HW + p] = acc[o] + wlds[WLDS_W + e * F + c * OC + o];
  }
}

extern "C" void kernel_launch(void* const* d_in, const int* in_sizes, int n_in,
                              void* d_out, int out_size, void* d_ws, size_t ws_size,
                              hipStream_t stream) {
  const float* x   = (const float*)d_in[0];
  const float* W   = (const float*)d_in[1];
  const float* b   = (const float*)d_in[2];
  const float* T   = (const float*)d_in[3];
  const int*   eta = (const int*)d_in[4];
  float* out = (float*)d_out;

  int* etabuf = (ws_size >= sizeof(int) * (size_t)HW)
                    ? (int*)d_ws
                    : ((int*)d_out) + (size_t)(F - 1) * HW;

  eta_kernel<<<HW / 256, 256, 0, stream>>>(T, eta, etabuf);
  expert_kernel<<<1024, 256, 0, stream>>>(x, W, b, etabuf, out);
}